// Round 1
// baseline (736.771 us; speedup 1.0000x reference)
//
#include <hip/hip_runtime.h>
#include <hip/hip_bf16.h>

// DLRM forward, f32 baseline.
// Shapes: B=2048, dense 13, emb 26x100000x64, interact 27 feats -> 351 pairs,
// top MLP 415->1024->512->256->1 (sigmoid).

#define BATCH 2048
#define VOCAB 100000
#define EMB 64
#define NSPARSE 26
#define NFEA 27
#define NPAIR 351           // 27*26/2
#define RDIM 415            // 64 + 351

// ---------------------------------------------------------------------------
// Generic fused GEMM + bias + activation:  C[M,N] = act(A[M,K] @ W[K,N] + b)
// block = 256 threads. Each block computes a ROWS x COLS tile of C.
// ACT: 0 = none, 1 = relu, 2 = sigmoid
// ---------------------------------------------------------------------------
template<int ROWS, int COLS, int KTILE, int ACT>
__global__ __launch_bounds__(256) void mlp_kernel(
    const float* __restrict__ A, const float* __restrict__ W,
    const float* __restrict__ bias, float* __restrict__ C,
    int M, int N, int K)
{
    constexpr int RG  = 256 / COLS;   // row-groups of threads
    constexpr int RPT = ROWS / RG;    // rows per thread

    __shared__ float As[ROWS][KTILE + 1];   // +1 pad: conflict-free across rows

    const int t    = threadIdx.x;
    const int nCB  = N / COLS;
    const int cb   = blockIdx.x % nCB;
    const int rb   = blockIdx.x / nCB;
    const int row0 = rb * ROWS;
    const int col  = cb * COLS + (t % COLS);
    const int rg   = t / COLS;

    float acc[RPT];
#pragma unroll
    for (int r = 0; r < RPT; ++r) acc[r] = 0.f;

    for (int k0 = 0; k0 < K; k0 += KTILE) {
        const int klen = min(KTILE, K - k0);
        // cooperative stage of the A tile (coalesced along K)
        for (int idx = t; idx < ROWS * KTILE; idx += 256) {
            const int r  = idx / KTILE;
            const int kk = idx % KTILE;
            As[r][kk] = (kk < klen) ? A[(size_t)(row0 + r) * K + k0 + kk] : 0.f;
        }
        __syncthreads();
        for (int kk = 0; kk < klen; ++kk) {
            const float w = W[(size_t)(k0 + kk) * N + col];
#pragma unroll
            for (int r = 0; r < RPT; ++r)
                acc[r] += As[rg * RPT + r][kk] * w;
        }
        __syncthreads();
    }

#pragma unroll
    for (int r = 0; r < RPT; ++r) {
        float v = acc[r] + bias[col];
        if (ACT == 1) v = fmaxf(v, 0.f);
        else if (ACT == 2) v = 1.f / (1.f + expf(-v));
        C[(size_t)(row0 + rg * RPT + r) * N + col] = v;
    }
}

// ---------------------------------------------------------------------------
// Embedding gather + pairwise dot interaction.  One block per batch row.
// Builds R[b, 0:64] = bot, R[b, 64+p] = dot(T_i, T_j), p = i*(i-1)/2 + j (i>j)
// ---------------------------------------------------------------------------
__global__ __launch_bounds__(256) void interact_kernel(
    const float* __restrict__ bot, const int* __restrict__ cat_idx,
    const float* __restrict__ tables, float* __restrict__ R)
{
    __shared__ float T[NFEA][EMB + 1];   // stride 65: banks (i+k)%32, conflict-free

    const int b    = blockIdx.x;
    const int t    = threadIdx.x;
    const int g    = t >> 6;     // 4 groups of 64 lanes
    const int lane = t & 63;

    // gather: group g handles features g, g+4, ... (feature 0 = bot row)
    for (int f = g; f < NFEA; f += 4) {
        if (f == 0) {
            T[0][lane] = bot[(size_t)b * EMB + lane];
        } else {
            const int j   = f - 1;
            const int idx = cat_idx[b * NSPARSE + j];
            T[f][lane] = tables[((size_t)j * VOCAB + idx) * EMB + lane];
        }
    }
    __syncthreads();

    // write bot portion of R
    if (t < EMB) R[(size_t)b * RDIM + t] = T[0][t];

    // pairwise dots
    for (int p = t; p < NPAIR; p += 256) {
        int i = (int)((1.0f + sqrtf(1.0f + 8.0f * (float)p)) * 0.5f);
        while (i * (i - 1) / 2 > p) --i;
        while ((i + 1) * i / 2 <= p) ++i;
        const int j = p - i * (i - 1) / 2;
        float s = 0.f;
#pragma unroll 16
        for (int k = 0; k < EMB; ++k) s += T[i][k] * T[j][k];
        R[(size_t)b * RDIM + EMB + p] = s;
    }
}

// ---------------------------------------------------------------------------
// Final layer: out[b] = sigmoid(dot(r2[b,:256], tw3) + tb3). One wave per row.
// ---------------------------------------------------------------------------
__global__ __launch_bounds__(256) void top3_kernel(
    const float* __restrict__ A, const float* __restrict__ w,
    const float* __restrict__ bias, float* __restrict__ out)
{
    const int gid  = blockIdx.x * 256 + threadIdx.x;
    const int row  = gid >> 6;
    const int lane = gid & 63;

    const float* a = A + (size_t)row * 256;
    float s = 0.f;
#pragma unroll
    for (int k = lane; k < 256; k += 64) s += a[k] * w[k];
#pragma unroll
    for (int off = 32; off; off >>= 1) s += __shfl_down(s, off);
    if (lane == 0) out[row] = 1.f / (1.f + expf(-(s + bias[0])));
}

// ---------------------------------------------------------------------------
extern "C" void kernel_launch(void* const* d_in, const int* in_sizes, int n_in,
                              void* d_out, int out_size, void* d_ws, size_t ws_size,
                              hipStream_t stream)
{
    const float* dense   = (const float*)d_in[0];
    const int*   cat_idx = (const int*)  d_in[1];
    const float* tables  = (const float*)d_in[2];
    const float* bw0 = (const float*)d_in[3];
    const float* bb0 = (const float*)d_in[4];
    const float* bw1 = (const float*)d_in[5];
    const float* bb1 = (const float*)d_in[6];
    const float* bw2 = (const float*)d_in[7];
    const float* bb2 = (const float*)d_in[8];
    const float* tw0 = (const float*)d_in[9];
    const float* tb0 = (const float*)d_in[10];
    const float* tw1 = (const float*)d_in[11];
    const float* tb1 = (const float*)d_in[12];
    const float* tw2 = (const float*)d_in[13];
    const float* tb2 = (const float*)d_in[14];
    const float* tw3 = (const float*)d_in[15];
    const float* tb3 = (const float*)d_in[16];

    float* ws  = (float*)d_ws;
    float* h0  = ws;                         // 2048 x 512
    float* h1  = h0  + (size_t)BATCH * 512;  // 2048 x 256
    float* bot = h1  + (size_t)BATCH * 256;  // 2048 x 64
    float* R   = bot + (size_t)BATCH * 64;   // 2048 x 415
    float* r0  = R   + (size_t)BATCH * RDIM; // 2048 x 1024
    float* r1  = r0  + (size_t)BATCH * 1024; // 2048 x 512
    float* r2  = r1  + (size_t)BATCH * 512;  // 2048 x 256
    float* out = (float*)d_out;              // 2048

    // bottom MLP
    mlp_kernel<16, 256, 16, 1><<<(512 / 256) * (BATCH / 16), 256, 0, stream>>>(
        dense, bw0, bb0, h0, BATCH, 512, 13);
    mlp_kernel<8, 256, 64, 1><<<(256 / 256) * (BATCH / 8), 256, 0, stream>>>(
        h0, bw1, bb1, h1, BATCH, 256, 512);
    mlp_kernel<8, 64, 64, 1><<<(64 / 64) * (BATCH / 8), 256, 0, stream>>>(
        h1, bw2, bb2, bot, BATCH, 64, 256);

    // gather + interaction
    interact_kernel<<<BATCH, 256, 0, stream>>>(bot, cat_idx, tables, R);

    // top MLP
    mlp_kernel<16, 256, 64, 1><<<(1024 / 256) * (BATCH / 16), 256, 0, stream>>>(
        R, tw0, tb0, r0, BATCH, 1024, RDIM);
    mlp_kernel<16, 256, 64, 1><<<(512 / 256) * (BATCH / 16), 256, 0, stream>>>(
        r0, tw1, tb1, r1, BATCH, 512, 1024);
    mlp_kernel<8, 256, 64, 1><<<(256 / 256) * (BATCH / 8), 256, 0, stream>>>(
        r1, tw2, tb2, r2, BATCH, 256, 512);
    top3_kernel<<<BATCH / 4, 256, 0, stream>>>(r2, tw3, tb3, out);
}

// Round 2
// 72.731 us; speedup vs baseline: 10.1301x; 10.1301x over previous
//
#include <hip/hip_runtime.h>
#include <hip/hip_bf16.h>

// DLRM forward, bf16-MFMA version.
// B=2048, dense 13, emb 26x100000x64, 27 feats -> 351 pairs,
// top MLP 415(->416 pad)->1024->512->256->1 sigmoid.

#define BATCH 2048
#define VOCAB 100000
#define EMB 64
#define NSPARSE 26
#define NFEA 27
#define NPAIR 351
#define RLD 416            // padded R row stride (415 -> 416)

typedef __attribute__((ext_vector_type(8))) __bf16 bf16x8;
typedef __attribute__((ext_vector_type(4))) float f32x4;
typedef __hip_bfloat16 bf16;

// async global->LDS, 16B per lane. LDS dest must be wave-uniform base + lane*16.
#define GLOAD16(g, l)                                                          \
    __builtin_amdgcn_global_load_lds(                                          \
        (const __attribute__((address_space(1))) unsigned int*)(g),            \
        (__attribute__((address_space(3))) unsigned int*)(l), 16, 0, 0)

// ---------------------------------------------------------------------------
// bf16 MFMA GEMM: C[M,ldC] = relu(A[M,K] @ Wt[N,K]^T + bias), all bf16 I/O,
// f32 accum. 64x64 tile / block, 256 thr = 4 waves (2x2 of 32x32 each),
// BK=32, K % 32 == 0. LDS tiles [64][32] bf16 (64B rows), XOR-swizzled:
// physical 16B-slot = nominal slot ^ ((row>>1)&3)  (both staged + read sides).
// ---------------------------------------------------------------------------
__global__ __launch_bounds__(256) void gemm_bf16(
    const bf16* __restrict__ A,   // [M][K]
    const bf16* __restrict__ Wt,  // [N][K]  (= W^T)
    const float* __restrict__ bias,
    bf16* __restrict__ C,         // [M][ldC]
    int M, int N, int K, int ldC)
{
    __shared__ __align__(16) bf16 As[64 * 32];
    __shared__ __align__(16) bf16 Bs[64 * 32];

    const int t   = threadIdx.x;
    const int nbn = N >> 6;
    const int bm  = blockIdx.x / nbn;
    const int bn  = blockIdx.x % nbn;
    const int row0 = bm << 6, n0 = bn << 6;

    const int wid  = t >> 6, lane = t & 63;
    const int wr   = wid >> 1, wc = wid & 1;
    const int lr   = lane & 15;     // row within 16x16 frag
    const int q    = lane >> 4;     // k-slot (8 bf16 = 16B each)

    // staging: thread t loads 16B -> LDS[t*16]; that is (row=t>>2, slot=t&3).
    // To realize the swizzled layout, fetch the swizzled global slot.
    const int srow = t >> 2, sslot = t & 3;
    const int sswz = sslot ^ ((srow >> 1) & 3);
    const char* gA = (const char*)(A  + (size_t)(row0 + srow) * K) + sswz * 16;
    const char* gB = (const char*)(Wt + (size_t)(n0   + srow) * K) + sswz * 16;
    char* lA = (char*)As + t * 16;
    char* lB = (char*)Bs + t * 16;

    f32x4 acc[2][2] = {};

    const int arow0 = wr * 32 + lr;   // + 16*m
    const int brow0 = wc * 32 + lr;   // + 16*n

    for (int k0 = 0; k0 < K; k0 += 32) {
        GLOAD16(gA + (size_t)k0 * 2, lA);
        GLOAD16(gB + (size_t)k0 * 2, lB);
        __syncthreads();   // drains vmcnt+lgkmcnt, then barrier

        bf16x8 af[2], bf[2];
#pragma unroll
        for (int m = 0; m < 2; ++m) {
            const int r = arow0 + 16 * m;
            af[m] = *(const bf16x8*)((const char*)As + r * 64 +
                                     ((q ^ ((r >> 1) & 3)) << 4));
        }
#pragma unroll
        for (int n = 0; n < 2; ++n) {
            const int r = brow0 + 16 * n;
            bf[n] = *(const bf16x8*)((const char*)Bs + r * 64 +
                                     ((q ^ ((r >> 1) & 3)) << 4));
        }
#pragma unroll
        for (int m = 0; m < 2; ++m)
#pragma unroll
            for (int n = 0; n < 2; ++n)
                acc[m][n] = __builtin_amdgcn_mfma_f32_16x16x32_bf16(
                    af[m], bf[n], acc[m][n], 0, 0, 0);
        __syncthreads();   // protect LDS before next stage
    }

    // epilogue: D layout col = lane&15, row = (lane>>4)*4 + i  (m89-verified)
#pragma unroll
    for (int n = 0; n < 2; ++n) {
        const int col = n0 + wc * 32 + 16 * n + lr;
        const float bv = bias[col];
#pragma unroll
        for (int m = 0; m < 2; ++m) {
#pragma unroll
            for (int i = 0; i < 4; ++i) {
                const int row = row0 + wr * 32 + 16 * m + q * 4 + i;
                float v = acc[m][n][i] + bv;
                v = fmaxf(v, 0.f);
                C[(size_t)row * ldC + col] = __float2bfloat16(v);
            }
        }
    }
}

// ---------------------------------------------------------------------------
// Fused weight convert+transpose: dst[n][kp] = bf16(src[k][n]), zero-pad k>=K.
// One 32x32 tile per block, LDS staged so both read and write are coalesced.
// ---------------------------------------------------------------------------
struct WConvArgs {
    const float* src[6];
    bf16*        dst[6];
    int K[6], N[6], Kp[6], t0[7];
};

__global__ __launch_bounds__(256) void wconv_kernel(WConvArgs a)
{
    __shared__ float Ts[32][33];
    int w = 0;
    while (w < 5 && (int)blockIdx.x >= a.t0[w + 1]) ++w;
    const int rel = blockIdx.x - a.t0[w];
    const int K = a.K[w], N = a.N[w], Kp = a.Kp[w];
    const int nbn = N >> 5;
    const int tk = rel / nbn, tn = rel % nbn;
    const int tx = threadIdx.x & 31, ty = threadIdx.x >> 5;

    const float* src = a.src[w];
    bf16* dst = a.dst[w];

#pragma unroll
    for (int rr = 0; rr < 4; ++rr) {
        const int k = tk * 32 + ty + rr * 8;
        const int n = tn * 32 + tx;
        Ts[ty + rr * 8][tx] = (k < K) ? src[(size_t)k * N + n] : 0.f;
    }
    __syncthreads();
#pragma unroll
    for (int rr = 0; rr < 4; ++rr) {
        const int n = tn * 32 + ty + rr * 8;
        const int kp = tk * 32 + tx;
        dst[(size_t)n * Kp + kp] = __float2bfloat16(Ts[tx][ty + rr * 8]);
    }
}

// dense [2048][13] f32 -> dense_bf [2048][32] bf16 zero-padded
__global__ __launch_bounds__(256) void densepad_kernel(
    const float* __restrict__ dense, bf16* __restrict__ out)
{
    const int i = blockIdx.x * 256 + threadIdx.x;   // over 2048*32
    const int b = i >> 5, c = i & 31;
    out[i] = (c < 13) ? __float2bfloat16(dense[b * 13 + c]) : __float2bfloat16(0.f);
}

// ---------------------------------------------------------------------------
// Embedding gather + pairwise dots. One block per batch row.
// bot (bf16) already sits in R[b][0:64]; writes R[b][64+p] and R[b][415]=0.
// ---------------------------------------------------------------------------
__global__ __launch_bounds__(256) void interact_kernel(
    const int* __restrict__ cat_idx, const float* __restrict__ tables,
    bf16* __restrict__ R)
{
    __shared__ float T[NFEA][EMB + 1];

    const int b    = blockIdx.x;
    const int t    = threadIdx.x;
    const int g    = t >> 6;
    const int lane = t & 63;
    bf16* Rrow = R + (size_t)b * RLD;

    for (int f = g; f < NFEA; f += 4) {
        if (f == 0) {
            T[0][lane] = __bfloat162float(Rrow[lane]);
        } else {
            const int j   = f - 1;
            const int idx = cat_idx[b * NSPARSE + j];
            T[f][lane] = tables[((size_t)j * VOCAB + idx) * EMB + lane];
        }
    }
    __syncthreads();

    if (t == 0) Rrow[415] = __float2bfloat16(0.f);

    for (int p = t; p < NPAIR; p += 256) {
        int i = (int)((1.0f + sqrtf(1.0f + 8.0f * (float)p)) * 0.5f);
        while (i * (i - 1) / 2 > p) --i;
        while ((i + 1) * i / 2 <= p) ++i;
        const int j = p - i * (i - 1) / 2;
        float s = 0.f;
#pragma unroll 16
        for (int k = 0; k < EMB; ++k) s += T[i][k] * T[j][k];
        Rrow[EMB + p] = __float2bfloat16(s);
    }
}

// final layer: out[b] = sigmoid(dot(r2[b,:256] (bf16), tw3 (f32)) + tb3)
__global__ __launch_bounds__(256) void top3_kernel(
    const bf16* __restrict__ A, const float* __restrict__ w,
    const float* __restrict__ bias, float* __restrict__ out)
{
    const int gid  = blockIdx.x * 256 + threadIdx.x;
    const int row  = gid >> 6;
    const int lane = gid & 63;

    const bf16* arow = A + (size_t)row * 256;
    float s = 0.f;
#pragma unroll
    for (int k = lane; k < 256; k += 64)
        s += __bfloat162float(arow[k]) * w[k];
#pragma unroll
    for (int off = 32; off; off >>= 1) s += __shfl_down(s, off);
    if (lane == 0) out[row] = 1.f / (1.f + expf(-(s + bias[0])));
}

// ---------------------------------------------------------------------------
extern "C" void kernel_launch(void* const* d_in, const int* in_sizes, int n_in,
                              void* d_out, int out_size, void* d_ws, size_t ws_size,
                              hipStream_t stream)
{
    const float* dense   = (const float*)d_in[0];
    const int*   cat_idx = (const int*)  d_in[1];
    const float* tables  = (const float*)d_in[2];
    const float* bw0 = (const float*)d_in[3];
    const float* bb0 = (const float*)d_in[4];
    const float* bw1 = (const float*)d_in[5];
    const float* bb1 = (const float*)d_in[6];
    const float* bw2 = (const float*)d_in[7];
    const float* bb2 = (const float*)d_in[8];
    const float* tw0 = (const float*)d_in[9];
    const float* tb0 = (const float*)d_in[10];
    const float* tw1 = (const float*)d_in[11];
    const float* tb1 = (const float*)d_in[12];
    const float* tw2 = (const float*)d_in[13];
    const float* tb2 = (const float*)d_in[14];
    const float* tw3 = (const float*)d_in[15];
    const float* tb3 = (const float*)d_in[16];

    bf16* p = (bf16*)d_ws;
    bf16* dense_bf = p; p += (size_t)BATCH * 32;
    bf16* h0   = p; p += (size_t)BATCH * 512;
    bf16* h1   = p; p += (size_t)BATCH * 256;
    bf16* R    = p; p += (size_t)BATCH * RLD;
    bf16* r0   = p; p += (size_t)BATCH * 1024;
    bf16* r1   = p; p += (size_t)BATCH * 512;
    bf16* r2   = p; p += (size_t)BATCH * 256;
    bf16* bw0t = p; p += 512 * 32;
    bf16* bw1t = p; p += 256 * 512;
    bf16* bw2t = p; p += 64 * 256;
    bf16* tw0t = p; p += 1024 * RLD;
    bf16* tw1t = p; p += 512 * 1024;
    bf16* tw2t = p; p += 256 * 512;
    float* out = (float*)d_out;

    // fused weight transpose+convert
    WConvArgs wa;
    wa.src[0] = bw0;  wa.dst[0] = bw0t; wa.K[0] = 13;   wa.N[0] = 512;  wa.Kp[0] = 32;
    wa.src[1] = bw1;  wa.dst[1] = bw1t; wa.K[1] = 512;  wa.N[1] = 256;  wa.Kp[1] = 512;
    wa.src[2] = bw2;  wa.dst[2] = bw2t; wa.K[2] = 256;  wa.N[2] = 64;   wa.Kp[2] = 256;
    wa.src[3] = tw0;  wa.dst[3] = tw0t; wa.K[3] = 415;  wa.N[3] = 1024; wa.Kp[3] = RLD;
    wa.src[4] = tw1;  wa.dst[4] = tw1t; wa.K[4] = 1024; wa.N[4] = 512;  wa.Kp[4] = 1024;
    wa.src[5] = tw2;  wa.dst[5] = tw2t; wa.K[5] = 512;  wa.N[5] = 256;  wa.Kp[5] = 512;
    int tiles = 0;
    for (int w = 0; w < 6; ++w) {
        wa.t0[w] = tiles;
        tiles += (wa.Kp[w] >> 5) * (wa.N[w] >> 5);
    }
    wa.t0[6] = tiles;   // 1216

    wconv_kernel<<<tiles, 256, 0, stream>>>(wa);
    densepad_kernel<<<(BATCH * 32) / 256, 256, 0, stream>>>(dense, dense_bf);

    // bottom MLP
    gemm_bf16<<<(BATCH / 64) * (512 / 64), 256, 0, stream>>>(
        dense_bf, bw0t, bb0, h0, BATCH, 512, 32, 512);
    gemm_bf16<<<(BATCH / 64) * (256 / 64), 256, 0, stream>>>(
        h0, bw1t, bb1, h1, BATCH, 256, 512, 256);
    gemm_bf16<<<(BATCH / 64) * (64 / 64), 256, 0, stream>>>(
        h1, bw2t, bb2, R, BATCH, 64, 256, RLD);   // bot -> R[:, :64]

    interact_kernel<<<BATCH, 256, 0, stream>>>(cat_idx, tables, R);

    // top MLP
    gemm_bf16<<<(BATCH / 64) * (1024 / 64), 256, 0, stream>>>(
        R, tw0t, tb0, r0, BATCH, 1024, RLD, 1024);
    gemm_bf16<<<(BATCH / 64) * (512 / 64), 256, 0, stream>>>(
        r0, tw1t, tb1, r1, BATCH, 512, 1024, 512);
    gemm_bf16<<<(BATCH / 64) * (256 / 64), 256, 0, stream>>>(
        r1, tw2t, tb2, r2, BATCH, 256, 512, 256);
    top3_kernel<<<BATCH / 4, 256, 0, stream>>>(r2, tw3, tb3, out);
}

// Round 3
// 67.745 us; speedup vs baseline: 10.8757x; 1.0736x over previous
//
#include <hip/hip_runtime.h>
#include <hip/hip_bf16.h>

// DLRM forward, bf16-MFMA, BK=64 pipeline.
// B=2048, dense 13, emb 26x100000x64, 27 feats -> 351 pairs,
// top MLP 415(->448 pad)->1024->512->256->1 sigmoid.

#define BATCH 2048
#define VOCAB 100000
#define EMB 64
#define NSPARSE 26
#define NFEA 27
#define NPAIR 351
#define RLD 448            // padded R row stride (415 -> 448, %64==0)

typedef __attribute__((ext_vector_type(8))) __bf16 bf16x8;
typedef __attribute__((ext_vector_type(4))) float f32x4;
typedef __hip_bfloat16 bf16;

#define GLOAD16(g, l)                                                          \
    __builtin_amdgcn_global_load_lds(                                          \
        (const __attribute__((address_space(1))) unsigned int*)(g),            \
        (__attribute__((address_space(3))) unsigned int*)(l), 16, 0, 0)

// ---------------------------------------------------------------------------
// bf16 MFMA GEMM: C[M,ldC] = relu(A[M,K] @ Wt[N,K]^T + bias), bf16 I/O,
// f32 accum. 64x64 tile / block, 256 thr = 4 waves (2x2 of 32x32).
// LDS rows swizzled in 16B slots:
//   BK=64 (128B rows): phys_slot = slot ^ (row & 7)       (2-way, free)
//   BK=32 ( 64B rows): phys_slot = slot ^ ((row >> 1) & 3) (2-way, free)
// Staged via global_load_lds with pre-swizzled global source (both-sides rule).
// DENSEPAD: A is raw f32 [M][13]; stage+convert+pad to K=32 in-kernel.
// ---------------------------------------------------------------------------
template<int BK, bool DENSEPAD>
__global__ __launch_bounds__(256) void gemm_bf16(
    const void* __restrict__ Araw,  // bf16 [M][K]  (or f32 [M][13] if DENSEPAD)
    const bf16* __restrict__ Wt,    // [N][K] = W^T
    const float* __restrict__ bias,
    bf16* __restrict__ C,           // [M][ldC]
    int M, int N, int K, int ldC)
{
    constexpr int ROWB   = BK * 2;        // bytes per LDS row
    constexpr int SLOTS  = BK / 8;        // 16B slots per row
    constexpr int PASSES = BK / 32;       // global_load_lds passes per matrix
    constexpr int RPP    = 256 / SLOTS;   // rows staged per pass

    __shared__ __align__(16) bf16 As[64 * BK];
    __shared__ __align__(16) bf16 Bs[64 * BK];

    const int t   = threadIdx.x;
    const int nbn = N >> 6;
    const int bm  = blockIdx.x / nbn;
    const int bn  = blockIdx.x % nbn;
    const int row0 = bm << 6, n0 = bn << 6;

    const int wid  = t >> 6, lane = t & 63;
    const int wr   = wid >> 1, wc = wid & 1;
    const int lr   = lane & 15;
    const int q    = lane >> 4;

#define SWZ(row, s) ((BK == 64) ? ((s) ^ ((row) & 7)) : ((s) ^ (((row) >> 1) & 3)))

    // staging geometry: pass p, thread t -> row, phys slot; fetch swizzled
    // global slot so LDS (linear dest) realizes the swizzled layout.
    const int srow  = t / SLOTS;
    const int sslot = t % SLOTS;

    const bf16* Ab[PASSES];
    const bf16* Bb[PASSES];
#pragma unroll
    for (int p = 0; p < PASSES; ++p) {
        const int r = p * RPP + srow;
        const int g = SWZ(r, sslot);
        if (!DENSEPAD)
            Ab[p] = (const bf16*)Araw + (size_t)(row0 + r) * K + g * 8;
        Bb[p] = Wt + (size_t)(n0 + r) * K + g * 8;
    }

    f32x4 acc[2][2] = {};

    for (int k0 = 0; k0 < K; k0 += BK) {
        if (DENSEPAD) {
            const float* Df = (const float*)Araw;
#pragma unroll
            for (int idx = t; idx < 64 * 32; idx += 256) {
                const int r = idx >> 5, c = idx & 31;
                const float v = (c < 13) ? Df[(size_t)(row0 + r) * 13 + c] : 0.f;
                As[r * 32 + SWZ(r, c >> 3) * 8 + (c & 7)] = __float2bfloat16(v);
            }
        } else {
#pragma unroll
            for (int p = 0; p < PASSES; ++p)
                GLOAD16(Ab[p] + k0, (char*)As + p * 4096 + t * 16);
        }
#pragma unroll
        for (int p = 0; p < PASSES; ++p)
            GLOAD16(Bb[p] + k0, (char*)Bs + p * 4096 + t * 16);
        __syncthreads();

        bf16x8 af[PASSES][2], bfr[PASSES][2];
#pragma unroll
        for (int kk = 0; kk < PASSES; ++kk) {
#pragma unroll
            for (int m = 0; m < 2; ++m) {
                const int r = wr * 32 + 16 * m + lr;
                af[kk][m] = *(const bf16x8*)((const char*)As + r * ROWB +
                                             SWZ(r, kk * 4 + q) * 16);
            }
#pragma unroll
            for (int n = 0; n < 2; ++n) {
                const int r = wc * 32 + 16 * n + lr;
                bfr[kk][n] = *(const bf16x8*)((const char*)Bs + r * ROWB +
                                              SWZ(r, kk * 4 + q) * 16);
            }
        }
#pragma unroll
        for (int kk = 0; kk < PASSES; ++kk)
#pragma unroll
            for (int m = 0; m < 2; ++m)
#pragma unroll
                for (int n = 0; n < 2; ++n)
                    acc[m][n] = __builtin_amdgcn_mfma_f32_16x16x32_bf16(
                        af[kk][m], bfr[kk][n], acc[m][n], 0, 0, 0);
        __syncthreads();
    }
#undef SWZ

    // D layout: col = lane&15, row = (lane>>4)*4 + i
#pragma unroll
    for (int n = 0; n < 2; ++n) {
        const int col = n0 + wc * 32 + 16 * n + lr;
        const float bv = bias[col];
#pragma unroll
        for (int m = 0; m < 2; ++m) {
#pragma unroll
            for (int i = 0; i < 4; ++i) {
                const int row = row0 + wr * 32 + 16 * m + q * 4 + i;
                float v = acc[m][n][i] + bv;
                v = fmaxf(v, 0.f);
                C[(size_t)row * ldC + col] = __float2bfloat16(v);
            }
        }
    }
}

// ---------------------------------------------------------------------------
// Weight convert+transpose: dst[n][kp] = bf16(src[k][n]), zero-pad k>=K.
// ---------------------------------------------------------------------------
struct WConvArgs {
    const float* src[6];
    bf16*        dst[6];
    int K[6], N[6], Kp[6], t0[7];
};

__global__ __launch_bounds__(256) void wconv_kernel(WConvArgs a)
{
    __shared__ float Ts[32][33];
    int w = 0;
    while (w < 5 && (int)blockIdx.x >= a.t0[w + 1]) ++w;
    const int rel = blockIdx.x - a.t0[w];
    const int K = a.K[w], N = a.N[w], Kp = a.Kp[w];
    const int nbn = N >> 5;
    const int tk = rel / nbn, tn = rel % nbn;
    const int tx = threadIdx.x & 31, ty = threadIdx.x >> 5;

    const float* src = a.src[w];
    bf16* dst = a.dst[w];

#pragma unroll
    for (int rr = 0; rr < 4; ++rr) {
        const int k = tk * 32 + ty + rr * 8;
        const int n = tn * 32 + tx;
        Ts[ty + rr * 8][tx] = (k < K) ? src[(size_t)k * N + n] : 0.f;
    }
    __syncthreads();
#pragma unroll
    for (int rr = 0; rr < 4; ++rr) {
        const int n = tn * 32 + ty + rr * 8;
        const int kp = tk * 32 + tx;
        dst[(size_t)n * Kp + kp] = __float2bfloat16(Ts[tx][ty + rr * 8]);
    }
}

// ---------------------------------------------------------------------------
// Embedding gather + pairwise dots. One block per batch row.
// bot (bf16) sits in R[b][0:64]; writes R[b][64+p], zero-pads [415,448).
// ---------------------------------------------------------------------------
__global__ __launch_bounds__(256) void interact_kernel(
    const int* __restrict__ cat_idx, const float* __restrict__ tables,
    bf16* __restrict__ R)
{
    __shared__ float T[NFEA][EMB + 1];

    const int b    = blockIdx.x;
    const int t    = threadIdx.x;
    const int g    = t >> 6;
    const int lane = t & 63;
    bf16* Rrow = R + (size_t)b * RLD;

    for (int f = g; f < NFEA; f += 4) {
        if (f == 0) {
            T[0][lane] = __bfloat162float(Rrow[lane]);
        } else {
            const int j   = f - 1;
            const int idx = cat_idx[b * NSPARSE + j];
            T[f][lane] = tables[((size_t)j * VOCAB + idx) * EMB + lane];
        }
    }
    __syncthreads();

    if (t < RLD - 415) Rrow[415 + t] = __float2bfloat16(0.f);

    for (int p = t; p < NPAIR; p += 256) {
        int i = (int)((1.0f + sqrtf(1.0f + 8.0f * (float)p)) * 0.5f);
        while (i * (i - 1) / 2 > p) --i;
        while ((i + 1) * i / 2 <= p) ++i;
        const int j = p - i * (i - 1) / 2;
        float s = 0.f;
#pragma unroll 16
        for (int k = 0; k < EMB; ++k) s += T[i][k] * T[j][k];
        Rrow[EMB + p] = __float2bfloat16(s);
    }
}

// final layer: out[b] = sigmoid(dot(r2[b,:256] (bf16), tw3 (f32)) + tb3)
__global__ __launch_bounds__(256) void top3_kernel(
    const bf16* __restrict__ A, const float* __restrict__ w,
    const float* __restrict__ bias, float* __restrict__ out)
{
    const int gid  = blockIdx.x * 256 + threadIdx.x;
    const int row  = gid >> 6;
    const int lane = gid & 63;

    const bf16* arow = A + (size_t)row * 256;
    float s = 0.f;
#pragma unroll
    for (int k = lane; k < 256; k += 64)
        s += __bfloat162float(arow[k]) * w[k];
#pragma unroll
    for (int off = 32; off; off >>= 1) s += __shfl_down(s, off);
    if (lane == 0) out[row] = 1.f / (1.f + expf(-(s + bias[0])));
}

// ---------------------------------------------------------------------------
extern "C" void kernel_launch(void* const* d_in, const int* in_sizes, int n_in,
                              void* d_out, int out_size, void* d_ws, size_t ws_size,
                              hipStream_t stream)
{
    const float* dense   = (const float*)d_in[0];
    const int*   cat_idx = (const int*)  d_in[1];
    const float* tables  = (const float*)d_in[2];
    const float* bw0 = (const float*)d_in[3];
    const float* bb0 = (const float*)d_in[4];
    const float* bw1 = (const float*)d_in[5];
    const float* bb1 = (const float*)d_in[6];
    const float* bw2 = (const float*)d_in[7];
    const float* bb2 = (const float*)d_in[8];
    const float* tw0 = (const float*)d_in[9];
    const float* tb0 = (const float*)d_in[10];
    const float* tw1 = (const float*)d_in[11];
    const float* tb1 = (const float*)d_in[12];
    const float* tw2 = (const float*)d_in[13];
    const float* tb2 = (const float*)d_in[14];
    const float* tw3 = (const float*)d_in[15];
    const float* tb3 = (const float*)d_in[16];

    bf16* p = (bf16*)d_ws;
    bf16* h0   = p; p += (size_t)BATCH * 512;
    bf16* h1   = p; p += (size_t)BATCH * 256;
    bf16* R    = p; p += (size_t)BATCH * RLD;
    bf16* r0   = p; p += (size_t)BATCH * 1024;
    bf16* r1   = p; p += (size_t)BATCH * 512;
    bf16* r2   = p; p += (size_t)BATCH * 256;
    bf16* bw0t = p; p += 512 * 32;
    bf16* bw1t = p; p += 256 * 512;
    bf16* bw2t = p; p += 64 * 256;
    bf16* tw0t = p; p += 1024 * RLD;
    bf16* tw1t = p; p += 512 * 1024;
    bf16* tw2t = p; p += 256 * 512;
    float* out = (float*)d_out;

    WConvArgs wa;
    wa.src[0] = bw0;  wa.dst[0] = bw0t; wa.K[0] = 13;   wa.N[0] = 512;  wa.Kp[0] = 32;
    wa.src[1] = bw1;  wa.dst[1] = bw1t; wa.K[1] = 512;  wa.N[1] = 256;  wa.Kp[1] = 512;
    wa.src[2] = bw2;  wa.dst[2] = bw2t; wa.K[2] = 256;  wa.N[2] = 64;   wa.Kp[2] = 256;
    wa.src[3] = tw0;  wa.dst[3] = tw0t; wa.K[3] = 415;  wa.N[3] = 1024; wa.Kp[3] = RLD;
    wa.src[4] = tw1;  wa.dst[4] = tw1t; wa.K[4] = 1024; wa.N[4] = 512;  wa.Kp[4] = 1024;
    wa.src[5] = tw2;  wa.dst[5] = tw2t; wa.K[5] = 512;  wa.N[5] = 256;  wa.Kp[5] = 512;
    int tiles = 0;
    for (int w = 0; w < 6; ++w) {
        wa.t0[w] = tiles;
        tiles += (wa.Kp[w] >> 5) * (wa.N[w] >> 5);
    }
    wa.t0[6] = tiles;

    wconv_kernel<<<tiles, 256, 0, stream>>>(wa);

    // bottom MLP (layer 0 fused: f32 dense staged+padded in-kernel)
    gemm_bf16<32, true ><<<(BATCH / 64) * (512 / 64), 256, 0, stream>>>(
        dense, bw0t, bb0, h0, BATCH, 512, 32, 512);
    gemm_bf16<64, false><<<(BATCH / 64) * (256 / 64), 256, 0, stream>>>(
        h0, bw1t, bb1, h1, BATCH, 256, 512, 256);
    gemm_bf16<64, false><<<(BATCH / 64) * (64 / 64), 256, 0, stream>>>(
        h1, bw2t, bb2, R, BATCH, 64, 256, RLD);   // bot -> R[:, :64]

    interact_kernel<<<BATCH, 256, 0, stream>>>(cat_idx, tables, R);

    // top MLP
    gemm_bf16<64, false><<<(BATCH / 64) * (1024 / 64), 256, 0, stream>>>(
        R, tw0t, tb0, r0, BATCH, 1024, RLD, 1024);
    gemm_bf16<64, false><<<(BATCH / 64) * (512 / 64), 256, 0, stream>>>(
        r0, tw1t, tb1, r1, BATCH, 512, 1024, 512);
    gemm_bf16<64, false><<<(BATCH / 64) * (256 / 64), 256, 0, stream>>>(
        r1, tw2t, tb2, r2, BATCH, 256, 512, 256);
    top3_kernel<<<BATCH / 4, 256, 0, stream>>>(r2, tw3, tb3, out);
}